// Round 9
// baseline (299.527 us; speedup 1.0000x reference)
//
#include <hip/hip_runtime.h>

// C3-style layer via MFMA implicit GEMM, R8 = R7 with the y-coverage fix:
// YCH 168 -> 176 (3*168=504 < 508 left rows 504..507 unwritten -> absmax 2.97).
// Persistent y-walk, 32-slot LDS row ring, phase-pipelined stage/compute.
// x[32,6,512,512] f32 -> out[32,16,508,508] f32 (5x5 VALID conv; sparse
// oc<-ic connectivity via zero weights in dense [16,6,5,5] kernel).
//
// GEMM per kx: K=(window_row, icp8), M=32=(2 output rows x 16 oc), N=32 px.
// A-frags (d-independent) precomputed by prep kernel (verified in R6).
// Ring: slot = gy & 31; phase p computes 8 rows [Y, Y+7] (reads rows
// [Y, Y+11]) while staging rows [Y+12, Y+19] -- disjoint mod 32.

#define OW 508
#define BX 64     // px per block strip
#define TCOL 68   // staged columns = BX + 4
#define QP 33     // uint4 pitch per column (odd -> minimal b128 bank aliasing)
#define RM 31     // ring mask (32 row slots)
#define YCH 176   // output rows per y-chunk (grid.y = 3; 3*176 = 528 >= 508)

typedef _Float16 h8 __attribute__((ext_vector_type(8)));
typedef _Float16 h2 __attribute__((ext_vector_type(2)));
typedef float f32x16 __attribute__((ext_vector_type(16)));

__device__ __constant__ int d_CH3[6][3] = {
    {0,1,2},{1,2,3},{2,3,4},{3,4,5},{0,4,5},{0,1,5}};
__device__ __constant__ int d_CH4[9][4] = {
    {0,1,2,3},{1,2,3,4},{2,3,4,5},{0,3,4,5},{0,1,4,5},
    {0,1,2,5},{0,1,3,4},{1,2,4,5},{0,2,3,5}};

// ws: bias f32[16] | AF ushort[15*64*8]
// AF[((kx*3+ch)*64 + lane)*8 + e]: A-frag: oc=lane&15, dy=(lane>>4)&1,
// rr=lane>>5, ky=ch*2+rr-dy; value W[oc][e][ky][kx] or 0.  (verified R6)
__global__ void prep_weights(const float* __restrict__ w3, const float* __restrict__ b3,
                             const float* __restrict__ w4, const float* __restrict__ b4,
                             const float* __restrict__ w6, const float* __restrict__ b6,
                             float* __restrict__ bias, unsigned short* __restrict__ AF) {
    __shared__ float Wfull[16 * 6 * 25];   // dense [oc][ic][tap]
    const int tid = threadIdx.x;
    for (int i = tid; i < 16 * 6 * 25; i += 256) Wfull[i] = 0.f;
    __syncthreads();
    for (int i = tid; i < 6 * 3 * 25; i += 256) {
        int oc = i / 75, r = i % 75, c = r / 25, t = r % 25;
        Wfull[(oc * 6 + d_CH3[oc][c]) * 25 + t] = w3[i];
    }
    for (int i = tid; i < 9 * 4 * 25; i += 256) {
        int o = i / 100, r = i % 100, c = r / 25, t = r % 25;
        Wfull[((6 + o) * 6 + d_CH4[o][c]) * 25 + t] = w4[i];
    }
    for (int i = tid; i < 6 * 25; i += 256) Wfull[15 * 150 + i] = w6[i];
    __syncthreads();
    for (int i = tid; i < 15 * 64 * 8; i += 256) {
        int e = i & 7, lane = (i >> 3) & 63, q = i >> 9;   // q = kx*3+ch
        int kx = q / 3, ch = q % 3;
        int oc = lane & 15, dy = (lane >> 4) & 1, rr = lane >> 5;
        int ky = ch * 2 + rr - dy;
        float w = 0.f;
        if (e < 6 && ky >= 0 && ky <= 4) w = Wfull[(oc * 6 + e) * 25 + ky * 5 + kx];
        _Float16 hw = (_Float16)w;
        AF[i] = __builtin_bit_cast(unsigned short, hw);
    }
    if (tid < 6)        bias[tid] = b3[tid];
    else if (tid < 15)  bias[tid] = b4[tid - 6];
    else if (tid == 15) bias[tid] = b6[0];
}

__global__ __launch_bounds__(256, 3) void conv_mfma(
        const float* __restrict__ x, const unsigned short* __restrict__ AF,
        const float* __restrict__ bias, float* __restrict__ out) {
    __shared__ uint4 T4[TCOL * QP];     // 35904 B -> 3 blocks/CU

    const int tid = threadIdx.x;
    const int gx0 = blockIdx.x * BX;
    const int y0  = blockIdx.y * YCH;
    const int bz  = blockIdx.z;
    const int yrows = min(YCH, OW - y0);
    const int nph = (yrows + 7) >> 3;
    const float* xb = x + (size_t)bz * 6 * 512 * 512;
    unsigned int* Tw = (unsigned int*)T4;

    // zero-fill ring once: ip=3 words (icp 6,7) stay zero forever
    for (int i = tid; i < TCOL * QP; i += 256) T4[i] = (uint4){0u, 0u, 0u, 0u};

    const int lane = tid & 63;
    const int h = lane >> 5;            // K-half / oc-half (verified R6 mapping)

    h8 afr[15];
    #pragma unroll
    for (int q = 0; q < 15; ++q)
        afr[q] = *reinterpret_cast<const h8*>(AF + (q * 64 + lane) * 8);

    f32x16 binit;
    #pragma unroll
    for (int reg = 0; reg < 16; ++reg)
        binit[reg] = bias[((reg & 3) + 8 * ((reg >> 2) & 1) + 4 * h) & 15];

    __syncthreads();    // zero-fill visible before any staging writes

    // ---- prologue: stage rows [y0, y0+11]
    for (int idx = tid; idx < 12 * 102; idx += 256) {
        int cp  = idx % 34;
        int ip  = (idx / 34) % 3;
        int row = idx / 102;
        int gy = y0 + row;
        int c = 2 * cp, gx = gx0 + c;
        float2 a = {0.f, 0.f}, b = {0.f, 0.f};
        if (gy < 512 && gx < 512) {
            a = *(const float2*)(xb + ((size_t)(2 * ip) * 512 + gy) * 512 + gx);
            b = *(const float2*)(xb + ((size_t)(2 * ip + 1) * 512 + gy) * 512 + gx);
        }
        h2 w0; w0.x = (_Float16)a.x; w0.y = (_Float16)b.x;
        h2 w1; w1.x = (_Float16)a.y; w1.y = (_Float16)b.y;
        int q0 = c * QP + (gy & RM);
        Tw[q0 * 4 + ip]        = __builtin_bit_cast(unsigned int, w0);
        Tw[(q0 + QP) * 4 + ip] = __builtin_bit_cast(unsigned int, w1);
    }
    __syncthreads();

    const int s  = (tid >> 6) & 1;      // strip within block
    const int dh = tid >> 7;            // d-half
    const int colb = s * 32 + (lane & 31);
    const int px = gx0 + colb;
    const bool pxok = (px < OW);
    const size_t cs = (size_t)OW * OW;
    float* ob = out + ((size_t)bz * 16 + 4 * h) * cs + px;

    int Y = y0;
    #pragma unroll 1
    for (int p = 0; p < nph; ++p, Y += 8) {
        // -- issue global loads for rows [Y+12, Y+19] (hide under MFMA)
        float2 la[4], lb[4];
        int wq[4], wip[4];
        #pragma unroll
        for (int k = 0; k < 4; ++k) {
            int idx = tid + k * 256;
            bool v = idx < 816;                 // 8 rows * 3 ip * 34 col-pairs
            int cp  = idx % 34;
            int ip  = (idx / 34) % 3;
            int row = idx / 102;
            int gy = Y + 12 + row;
            int c = 2 * cp, gx = gx0 + c;
            la[k] = (float2){0.f, 0.f}; lb[k] = (float2){0.f, 0.f};
            if (v && gy < 512 && gx < 512) {
                la[k] = *(const float2*)(xb + ((size_t)(2 * ip) * 512 + gy) * 512 + gx);
                lb[k] = *(const float2*)(xb + ((size_t)(2 * ip + 1) * 512 + gy) * 512 + gx);
            }
            wq[k]  = v ? (c * QP + (gy & RM)) : -1;
            wip[k] = ip;
        }

        // -- compute: 2 independent MFMA chains (rows Y+4dh+0, Y+4dh+2)
        #pragma unroll
        for (int dd = 0; dd < 4; dd += 2) {
            const int Yd = Y + 4 * dh + dd;     // output row of dy=0
            const int sb = Yd + h;
            f32x16 acc = binit;
            #pragma unroll
            for (int kx = 0; kx < 5; ++kx) {
                const uint4* cb = &T4[(colb + kx) * QP];
                #pragma unroll
                for (int ch = 0; ch < 3; ++ch) {
                    h8 bfr = *reinterpret_cast<const h8*>(&cb[(sb + 2 * ch) & RM]);
                    acc = __builtin_amdgcn_mfma_f32_32x32x16_f16(afr[kx * 3 + ch], bfr, acc, 0, 0, 0);
                }
            }
            #pragma unroll
            for (int dy = 0; dy < 2; ++dy) {
                const int oy = Yd + dy;
                if (oy < OW && pxok) {
                    #pragma unroll
                    for (int r8 = 0; r8 < 8; ++r8) {
                        const int reg = dy * 8 + r8;
                        const int ocb = (reg & 3) + 8 * ((reg >> 2) & 1);
                        ob[(size_t)ocb * cs + (size_t)oy * OW] = acc[reg];
                    }
                }
            }
        }

        // -- commit staged rows to ring (slots disjoint from this phase's reads)
        #pragma unroll
        for (int k = 0; k < 4; ++k) {
            if (wq[k] >= 0) {
                h2 w0; w0.x = (_Float16)la[k].x; w0.y = (_Float16)lb[k].x;
                h2 w1; w1.x = (_Float16)la[k].y; w1.y = (_Float16)lb[k].y;
                Tw[wq[k] * 4 + wip[k]]        = __builtin_bit_cast(unsigned int, w0);
                Tw[(wq[k] + QP) * 4 + wip[k]] = __builtin_bit_cast(unsigned int, w1);
            }
        }
        __syncthreads();
    }
}

extern "C" void kernel_launch(void* const* d_in, const int* in_sizes, int n_in,
                              void* d_out, int out_size, void* d_ws, size_t ws_size,
                              hipStream_t stream) {
    const float* x  = (const float*)d_in[0];
    const float* w3 = (const float*)d_in[1];
    const float* b3 = (const float*)d_in[2];
    const float* w4 = (const float*)d_in[3];
    const float* b4 = (const float*)d_in[4];
    const float* w6 = (const float*)d_in[5];
    const float* b6 = (const float*)d_in[6];
    float* out = (float*)d_out;

    float* bias        = (float*)d_ws;                    // 16 f32
    unsigned short* AF = (unsigned short*)(bias + 16);    // 7680 u16

    prep_weights<<<1, 256, 0, stream>>>(w3, b3, w4, b4, w6, b6, bias, AF);

    dim3 grid((OW + BX - 1) / BX, 3, 32);   // 8 strips x 3 y-chunks x 32 batch
    conv_mfma<<<grid, 256, 0, stream>>>(x, AF, bias, out);
}